// Round 2
// baseline (971.792 us; speedup 1.0000x reference)
//
#include <hip/hip_runtime.h>
#include <math.h>

// ---------------- common helpers ----------------
typedef short bf16x8 __attribute__((ext_vector_type(8)));
typedef float f32x4 __attribute__((ext_vector_type(4)));

#define LOG2E 1.4426950408889634f
#define GSCALE 0.6451712903225806f   /* 1 - 11/31 + 1e-5 */

__device__ __forceinline__ float bf2f(unsigned short h) {
    union { unsigned u; float f; } v; v.u = ((unsigned)h) << 16; return v.f;
}
__device__ __forceinline__ unsigned short f2bf(float f) {
    union { float f; unsigned u; } v; v.f = f;
    unsigned r = v.u + 0x7FFFu + ((v.u >> 16) & 1u);
    return (unsigned short)(r >> 16);
}

#define GLD16(lds, g)                                                          \
    __builtin_amdgcn_global_load_lds(                                          \
        (const __attribute__((address_space(1))) void*)(g),                    \
        (__attribute__((address_space(3))) void*)(lds), 16, 0, 0)

// ---------------- f32 -> bf16 conversion ----------------
struct us4 { unsigned short a, b, c, d; };
__global__ __launch_bounds__(256) void cvt_f32_bf16(
    const float* __restrict__ src, unsigned short* __restrict__ dst, int n4)
{
    int i = blockIdx.x * 256 + threadIdx.x;
    if (i < n4) {
        float4 v = ((const float4*)src)[i];
        us4 o = { f2bf(v.x), f2bf(v.y), f2bf(v.z), f2bf(v.w) };
        ((us4*)dst)[i] = o;
    }
}

// ---------------- GEMM: C[M][N] = A[M][K] @ Bt[N][K]^T (bf16, f32 acc) ------
// EPI 0: scatter epilogue -> Q/K/V [b][h][t][d] (bf16)
// EPI 1: sigmoid -> C (bf16)
// EPI 2: plain  -> C (f32)
template <int EPI>
__global__ __launch_bounds__(256) void gemm_bt(
    const unsigned short* __restrict__ A, const unsigned short* __restrict__ Bt,
    void* __restrict__ Cv,
    unsigned short* __restrict__ Qp, unsigned short* __restrict__ Kp,
    unsigned short* __restrict__ Vp, int M, int N, int K)
{
    __shared__ unsigned short lA[128 * 32];
    __shared__ unsigned short lB[128 * 32];
    const int tid  = threadIdx.x;
    const int bn   = blockIdx.x, bm = blockIdx.y;
    const int lane = tid & 63, wave = tid >> 6;
    const int quad = lane >> 4, lr = lane & 15;
    const int wm   = (wave >> 1) * 64, wn = (wave & 1) * 64;
    f32x4 acc[4][4] = {};

    const long long abase = ((long long)bm * 128) * K;
    const long long bbase = ((long long)bn * 128) * K;

    for (int kt = 0; kt < K; kt += 32) {
        __syncthreads();
#pragma unroll
        for (int r = 0; r < 2; ++r) {
            int c   = r * 256 + tid;
            int row = c >> 2, c8 = (c & 3) << 3;
            GLD16(lA + c * 8, A + abase + (long long)row * K + kt + c8);
            GLD16(lB + c * 8, Bt + bbase + (long long)row * K + kt + c8);
        }
        __syncthreads();
        bf16x8 af[4], bfv[4];
#pragma unroll
        for (int i = 0; i < 4; ++i)
            af[i] = *(const bf16x8*)(lA + (wm + i * 16 + lr) * 32 + quad * 8);
#pragma unroll
        for (int j = 0; j < 4; ++j)
            bfv[j] = *(const bf16x8*)(lB + (wn + j * 16 + lr) * 32 + quad * 8);
#pragma unroll
        for (int i = 0; i < 4; ++i)
#pragma unroll
            for (int j = 0; j < 4; ++j)
                acc[i][j] = __builtin_amdgcn_mfma_f32_16x16x32_bf16(
                    af[i], bfv[j], acc[i][j], 0, 0, 0);
    }

#pragma unroll
    for (int i = 0; i < 4; ++i)
#pragma unroll
        for (int j = 0; j < 4; ++j)
#pragma unroll
            for (int r = 0; r < 4; ++r) {
                int row = bm * 128 + wm + i * 16 + quad * 4 + r;
                int col = bn * 128 + wn + j * 16 + lr;
                float v = acc[i][j][r];
                if (EPI == 0) {
                    int tens = col >> 11, h = (col >> 7) & 15, e = col & 127;
                    int b = row >> 12, t = row & 4095;
                    long long dst = (((long long)(b * 16 + h)) * 4096 + t) * 128 + e;
                    unsigned short* P = (tens == 0) ? Qp : ((tens == 1) ? Kp : Vp);
                    P[dst] = f2bf(v);
                } else if (EPI == 1) {
                    v = 1.0f / (1.0f + __expf(-v));
                    ((unsigned short*)Cv)[(long long)row * N + col] = f2bf(v);
                } else {
                    ((float*)Cv)[(long long)row * N + col] = v;
                }
            }
}

// ---------------- RMSNorm + RoPE on q,k (in place, [b][h][t][d]) -----------
__global__ __launch_bounds__(256) void norm_rope(
    unsigned short* __restrict__ Qp, unsigned short* __restrict__ Kp,
    const float* __restrict__ qw, const float* __restrict__ kw,
    const int* __restrict__ pos_ids)
{
    const int bid  = blockIdx.x;            // b*16384 + h*1024 + tg
    const int tg   = bid & 1023, h = (bid >> 10) & 15, b = bid >> 14;
    const int wave = threadIdx.x >> 6, lane = threadIdx.x & 63;
    const int t    = tg * 4 + wave;
    const long long rowbase = (((long long)(b * 16 + h)) * 4096 + t) * 128;
    const int pos = pos_ids[b * 4096 + t];
    const int d0  = lane * 2;

    float c0 = 1.f, s0 = 0.f, c1 = 1.f, s1 = 0.f;
    if (lane < 32) {
        float fj0 = (float)(d0 & 31), fj1 = (float)((d0 + 1) & 31);
        float if0 = exp2f(-fj0 * 0.4152410118609203f);  // log2(10000)/32
        float if1 = exp2f(-fj1 * 0.4152410118609203f);
        sincosf((float)pos * if0, &s0, &c0);
        sincosf((float)pos * if1, &s1, &c1);
    }
    const float w0q = qw[d0], w1q = qw[d0 + 1];
    const float w0k = kw[d0], w1k = kw[d0 + 1];

#pragma unroll
    for (int which = 0; which < 2; ++which) {
        unsigned short* P = which ? Kp : Qp;
        float w0 = which ? w0k : w0q, w1 = which ? w1k : w1q;
        unsigned u = *(const unsigned*)(P + rowbase + d0);
        float x0 = bf2f(u & 0xFFFF), x1 = bf2f(u >> 16);
        float ss = x0 * x0 + x1 * x1;
#pragma unroll
        for (int off = 32; off; off >>= 1) ss += __shfl_xor(ss, off);
        float r  = rsqrtf(ss * (1.0f / 128.0f) + 1e-6f);
        float xn0 = x0 * r * w0;
        float xn1 = x1 * r * w1;
        float p0 = __shfl_xor(xn0, 16);
        float p1 = __shfl_xor(xn1, 16);
        float y0, y1;
        if (d0 < 32)      { y0 = xn0 * c0 - p0 * s0; y1 = xn1 * c1 - p1 * s1; }
        else if (d0 < 64) { y0 = xn0 * c0 + p0 * s0; y1 = xn1 * c1 + p1 * s1; }
        else              { y0 = xn0; y1 = xn1; }
        if (which == 0) { y0 *= 0.08838834764831845f; y1 *= 0.08838834764831845f; }
        *(unsigned*)(P + rowbase + d0) =
            (unsigned)f2bf(y0) | ((unsigned)f2bf(y1) << 16);
    }
}

// ---------------- GLA chunk scan ----------------
// grid = B*H*4 blocks; block (b,h,eb) handles v/e columns [eb*32, eb*32+32)
// Folding: q~[c] = q[c]*exp(g c); kdec'[c] = exp(g(64-c)); S' = exp(g)*S;
// att residual column factor exp(-g c2). Exact algebra, no approximation.
__global__ __launch_bounds__(256) void gla(
    const unsigned short* __restrict__ Qp, const unsigned short* __restrict__ Kp,
    const unsigned short* __restrict__ Vp, unsigned short* __restrict__ Op)
{
    __shared__ unsigned short sQ[64 * 128];
    __shared__ unsigned short sK[64 * 128];   // becomes sKT[128][64] after att
    __shared__ unsigned short sVT[32 * 64];
    __shared__ unsigned short sAtt[64 * 64];
    __shared__ unsigned short sST[32 * 128];  // S'^T slice, bf16 copy for MFMA

    const int bid = blockIdx.x;
    const int eb = bid & 3, h = (bid >> 2) & 15, b = bid >> 6;
    const int e0 = eb * 32;
    const int tid = threadIdx.x, wave = tid >> 6, lane = tid & 63;
    const int quad = lane >> 4, lr = lane & 15;
    const float gl2 = -exp2f(-0.5f * (float)(h + 1)) * GSCALE * LOG2E;
    const float chd = exp2f(gl2 * 64.0f);

    const long long base = (((long long)(b * 16 + h)) * 4096) * 128;

    for (int i = tid; i < 32 * 128; i += 256) sST[i] = 0;
    f32x4 Sacc[4] = {};

    const int cS  = wave * 16 + lr;            // A-operand row for att / o
    const int ei  = wave & 1, djb = (wave >> 1) * 4;  // S-update partition
    const int td  = tid >> 1, tc0 = (tid & 1) * 32;   // transpose mapping

    for (int n = 0; n < 64; ++n) {
        __syncthreads();  // B1: prev chunk's LDS reads done
        const long long rb = base + (long long)n * 64 * 128;
        // stage sQ (scaled by exp(g c))
#pragma unroll
        for (int rr = 0; rr < 4; ++rr) {
            int idx = rr * 256 + tid;
            int c = idx >> 4, d8 = (idx & 15) << 3;
            union { uint4 v; unsigned short s[8]; } in, ou;
            in.v = *(const uint4*)(Qp + rb + c * 128 + d8);
            float sc = exp2f(gl2 * (float)c);
#pragma unroll
            for (int j = 0; j < 8; ++j) ou.s[j] = f2bf(bf2f(in.s[j]) * sc);
            *(uint4*)(sQ + c * 128 + d8) = ou.v;
        }
        // stage sK (raw)
#pragma unroll
        for (int rr = 0; rr < 4; ++rr) {
            int idx = rr * 256 + tid;
            int c = idx >> 4, d8 = (idx & 15) << 3;
            *(uint4*)(sK + c * 128 + d8) = *(const uint4*)(Kp + rb + c * 128 + d8);
        }
        // stage sVT (transposed v slice)
        {
            int c = tid & 63, e8 = (tid >> 6) * 8;
            union { uint4 v; unsigned short s[8]; } in;
            in.v = *(const uint4*)(Vp + rb + c * 128 + e0 + e8);
#pragma unroll
            for (int j = 0; j < 8; ++j) sVT[(e8 + j) * 64 + c] = in.s[j];
        }
        __syncthreads();  // B2: staging visible (incl. prev sST update)

        // inter: o += q~ @ S'^T   (uses OLD S')
        f32x4 oacc[2] = {};
        bf16x8 qf[4];
#pragma unroll
        for (int ks = 0; ks < 4; ++ks)
            qf[ks] = *(const bf16x8*)(sQ + cS * 128 + ks * 32 + quad * 8);
#pragma unroll
        for (int ej = 0; ej < 2; ++ej)
#pragma unroll
            for (int ks = 0; ks < 4; ++ks) {
                bf16x8 bf = *(const bf16x8*)(sST + (ej * 16 + lr) * 128 + ks * 32 + quad * 8);
                oacc[ej] = __builtin_amdgcn_mfma_f32_16x16x32_bf16(qf[ks], bf, oacc[ej], 0, 0, 0);
            }
        // att~ = q~ @ k^T
        f32x4 aacc[4] = {};
#pragma unroll
        for (int nj = 0; nj < 4; ++nj)
#pragma unroll
            for (int ks = 0; ks < 4; ++ks) {
                bf16x8 bf = *(const bf16x8*)(sK + (nj * 16 + lr) * 128 + ks * 32 + quad * 8);
                aacc[nj] = __builtin_amdgcn_mfma_f32_16x16x32_bf16(qf[ks], bf, aacc[nj], 0, 0, 0);
            }
        // transpose-read k for kT (reads sK)
        float kv[32];
#pragma unroll
        for (int i = 0; i < 32; ++i) kv[i] = bf2f(sK[(tc0 + i) * 128 + td]);
        __syncthreads();  // B3: all sK/sST reads done

        // masked att write
#pragma unroll
        for (int nj = 0; nj < 4; ++nj) {
            int c2 = nj * 16 + lr;
            float colf = exp2f(-gl2 * (float)c2);
#pragma unroll
            for (int r = 0; r < 4; ++r) {
                int c = wave * 16 + quad * 4 + r;
                float v = (c >= c2) ? aacc[nj][r] * colf : 0.0f;
                sAtt[c * 64 + c2] = f2bf(v);
            }
        }
        // kT write (overwrites sK region), with kdec' = exp(g(64-c))
#pragma unroll
        for (int i = 0; i < 32; ++i) {
            int c = tc0 + i;
            sK[td * 64 + c] = f2bf(kv[i] * exp2f(gl2 * (float)(64 - c)));
        }
        // decay S'
#pragma unroll
        for (int s = 0; s < 4; ++s)
#pragma unroll
            for (int r = 0; r < 4; ++r) Sacc[s][r] *= chd;
        __syncthreads();  // B4

        // intra: o += att @ v
#pragma unroll
        for (int ej = 0; ej < 2; ++ej)
#pragma unroll
            for (int ks = 0; ks < 2; ++ks) {
                bf16x8 af = *(const bf16x8*)(sAtt + cS * 64 + ks * 32 + quad * 8);
                bf16x8 bf = *(const bf16x8*)(sVT + (ej * 16 + lr) * 64 + ks * 32 + quad * 8);
                oacc[ej] = __builtin_amdgcn_mfma_f32_16x16x32_bf16(af, bf, oacc[ej], 0, 0, 0);
            }
        // S'^T update: S'^T[e][d] += sum_c vT[e][c] * kT'[d][c]
#pragma unroll
        for (int s = 0; s < 4; ++s)
#pragma unroll
            for (int ks = 0; ks < 2; ++ks) {
                bf16x8 af = *(const bf16x8*)(sVT + (ei * 16 + lr) * 64 + ks * 32 + quad * 8);
                bf16x8 bf = *(const bf16x8*)(sK + ((djb + s) * 16 + lr) * 64 + ks * 32 + quad * 8);
                Sacc[s] = __builtin_amdgcn_mfma_f32_16x16x32_bf16(af, bf, Sacc[s], 0, 0, 0);
            }
        // write o chunk  [b][t][h*128 + e0 + e]
#pragma unroll
        for (int ej = 0; ej < 2; ++ej)
#pragma unroll
            for (int r = 0; r < 4; ++r) {
                int c = wave * 16 + quad * 4 + r;
                long long orow = ((long long)(b * 4096 + n * 64 + c)) * 2048 + h * 128 + e0 + ej * 16 + lr;
                Op[orow] = f2bf(oacc[ej][r]);
            }
        // publish bf16 S'^T for next chunk's inter
#pragma unroll
        for (int s = 0; s < 4; ++s)
#pragma unroll
            for (int r = 0; r < 4; ++r)
                sST[(ei * 16 + quad * 4 + r) * 128 + (djb + s) * 16 + lr] = f2bf(Sacc[s][r]);
    }
}

// ---------------- per-head RMSNorm * gate (in place on O) ------------------
__global__ __launch_bounds__(256) void gnorm_gate(
    unsigned short* __restrict__ O, const unsigned short* __restrict__ G,
    const float* __restrict__ W)
{
    const int bt = blockIdx.x;
    const int wave = threadIdx.x >> 6, lane = threadIdx.x & 63;
    const long long rb = (long long)bt * 2048;
#pragma unroll
    for (int i = 0; i < 4; ++i) {
        int hh = wave + i * 4;
        long long off = rb + hh * 128 + lane * 2;
        unsigned u = *(const unsigned*)(O + off);
        float x0 = bf2f(u & 0xFFFF), x1 = bf2f(u >> 16);
        float ss = x0 * x0 + x1 * x1;
#pragma unroll
        for (int o2 = 32; o2; o2 >>= 1) ss += __shfl_xor(ss, o2);
        float r = rsqrtf(ss * (1.0f / 128.0f) + 1e-6f);
        unsigned ug = *(const unsigned*)(G + off);
        float w0 = W[hh * 128 + lane * 2], w1 = W[hh * 128 + lane * 2 + 1];
        float y0 = x0 * r * w0 * bf2f(ug & 0xFFFF);
        float y1 = x1 * r * w1 * bf2f(ug >> 16);
        *(unsigned*)(O + off) = (unsigned)f2bf(y0) | ((unsigned)f2bf(y1) << 16);
    }
}

// ---------------- launcher ----------------
extern "C" void kernel_launch(void* const* d_in, const int* in_sizes, int n_in,
                              void* d_out, int out_size, void* d_ws, size_t ws_size,
                              hipStream_t stream)
{
    const float* hid   = (const float*)d_in[0];
    const float* w_qkv = (const float*)d_in[1];
    const float* q_ln  = (const float*)d_in[2];
    const float* k_ln  = (const float*)d_in[3];
    const float* g_nw  = (const float*)d_in[4];
    const float* w_g   = (const float*)d_in[5];
    const float* w_d   = (const float*)d_in[6];
    const int*   pos   = (const int*)d_in[7];

    const size_t PLANE = (size_t)2 * 16 * 4096 * 128;  // 16.78M elems
    unsigned short* Qp    = (unsigned short*)d_ws;
    unsigned short* Kp    = Qp + PLANE;
    unsigned short* Vp    = Kp + PLANE;
    unsigned short* Ob    = Vp + PLANE;
    unsigned short* Gb    = Ob + PLANE;
    unsigned short* hidb  = Gb + PLANE;                  // 8192*2048
    unsigned short* wqkvb = hidb + (size_t)8192 * 2048;  // 6144*2048
    unsigned short* wgb   = wqkvb + (size_t)6144 * 2048; // 2048*2048
    unsigned short* wdb   = wgb + (size_t)2048 * 2048;   // 2048*2048

    dim3 blk(256);
    // f32 -> bf16 conversions
    cvt_f32_bf16<<<(8192 * 2048 / 4 + 255) / 256, blk, 0, stream>>>(hid, hidb, 8192 * 2048 / 4);
    cvt_f32_bf16<<<(6144 * 2048 / 4 + 255) / 256, blk, 0, stream>>>(w_qkv, wqkvb, 6144 * 2048 / 4);
    cvt_f32_bf16<<<(2048 * 2048 / 4 + 255) / 256, blk, 0, stream>>>(w_g, wgb, 2048 * 2048 / 4);
    cvt_f32_bf16<<<(2048 * 2048 / 4 + 255) / 256, blk, 0, stream>>>(w_d, wdb, 2048 * 2048 / 4);

    // QKV projection, scatter to [b][h][t][d]
    gemm_bt<0><<<dim3(48, 64), blk, 0, stream>>>(hidb, wqkvb, nullptr, Qp, Kp, Vp,
                                                 8192, 6144, 2048);
    // q/k rmsnorm + rope (+ q * D^-0.5), in place
    norm_rope<<<32768, blk, 0, stream>>>(Qp, Kp, q_ln, k_ln, pos);
    // gate projection + sigmoid
    gemm_bt<1><<<dim3(16, 64), blk, 0, stream>>>(hidb, wgb, Gb, nullptr, nullptr,
                                                 nullptr, 8192, 2048, 2048);
    // linear-attention chunk scan
    gla<<<128, blk, 0, stream>>>(Qp, Kp, Vp, Ob);
    // group rmsnorm * gate (in place)
    gnorm_gate<<<8192, blk, 0, stream>>>(Ob, Gb, g_nw);
    // output projection -> f32 d_out
    gemm_bt<2><<<dim3(16, 64), blk, 0, stream>>>(Ob, wdb, d_out, nullptr, nullptr,
                                                 nullptr, 8192, 2048, 2048);
}

// Round 3
// 793.107 us; speedup vs baseline: 1.2253x; 1.2253x over previous
//
#include <hip/hip_runtime.h>
#include <math.h>

// ---------------- common helpers ----------------
typedef short bf16x8 __attribute__((ext_vector_type(8)));
typedef float f32x4 __attribute__((ext_vector_type(4)));

#define LOG2E 1.4426950408889634f
#define GSCALE 0.6451712903225806f   /* 1 - 11/31 + 1e-5 */

__device__ __forceinline__ float bf2f(unsigned short h) {
    union { unsigned u; float f; } v; v.u = ((unsigned)h) << 16; return v.f;
}
__device__ __forceinline__ unsigned short f2bf(float f) {
    union { float f; unsigned u; } v; v.f = f;
    unsigned r = v.u + 0x7FFFu + ((v.u >> 16) & 1u);
    return (unsigned short)(r >> 16);
}

#define GLD16(lds, g)                                                          \
    __builtin_amdgcn_global_load_lds(                                          \
        (const __attribute__((address_space(1))) void*)(g),                    \
        (__attribute__((address_space(3))) void*)(lds), 16, 0, 0)

#define MFMA16(a, b, c) __builtin_amdgcn_mfma_f32_16x16x32_bf16(a, b, c, 0, 0, 0)

// ---------------- f32 -> bf16 conversion ----------------
struct us4 { unsigned short a, b, c, d; };
__global__ __launch_bounds__(256) void cvt_f32_bf16(
    const float* __restrict__ src, unsigned short* __restrict__ dst, int n4)
{
    int i = blockIdx.x * 256 + threadIdx.x;
    if (i < n4) {
        float4 v = ((const float4*)src)[i];
        us4 o = { f2bf(v.x), f2bf(v.y), f2bf(v.z), f2bf(v.w) };
        ((us4*)dst)[i] = o;
    }
}

// ---------------- GEMM: C[M][N] = A[M][K] @ Bt[N][K]^T (bf16, f32 acc) ------
// EPI 0: scatter epilogue -> Q/K/V [b][h][t][d] (bf16)
// EPI 1: sigmoid -> C (bf16)
// EPI 2: plain  -> C (f32)
template <int EPI>
__global__ __launch_bounds__(256) void gemm_bt(
    const unsigned short* __restrict__ A, const unsigned short* __restrict__ Bt,
    void* __restrict__ Cv,
    unsigned short* __restrict__ Qp, unsigned short* __restrict__ Kp,
    unsigned short* __restrict__ Vp, int M, int N, int K)
{
    __shared__ __attribute__((aligned(16))) unsigned short lA[128 * 32];
    __shared__ __attribute__((aligned(16))) unsigned short lB[128 * 32];
    const int tid  = threadIdx.x;
    const int bn   = blockIdx.x, bm = blockIdx.y;
    const int lane = tid & 63, wave = tid >> 6;
    const int quad = lane >> 4, lr = lane & 15;
    const int wm   = (wave >> 1) * 64, wn = (wave & 1) * 64;
    f32x4 acc[4][4] = {};

    const long long abase = ((long long)bm * 128) * K;
    const long long bbase = ((long long)bn * 128) * K;

    for (int kt = 0; kt < K; kt += 32) {
        __syncthreads();
#pragma unroll
        for (int r = 0; r < 2; ++r) {
            int c   = r * 256 + tid;
            int row = c >> 2, c8 = (c & 3) << 3;
            GLD16(lA + c * 8, A + abase + (long long)row * K + kt + c8);
            GLD16(lB + c * 8, Bt + bbase + (long long)row * K + kt + c8);
        }
        __syncthreads();
        bf16x8 af[4], bfv[4];
#pragma unroll
        for (int i = 0; i < 4; ++i)
            af[i] = *(const bf16x8*)(lA + (wm + i * 16 + lr) * 32 + quad * 8);
#pragma unroll
        for (int j = 0; j < 4; ++j)
            bfv[j] = *(const bf16x8*)(lB + (wn + j * 16 + lr) * 32 + quad * 8);
#pragma unroll
        for (int i = 0; i < 4; ++i)
#pragma unroll
            for (int j = 0; j < 4; ++j)
                acc[i][j] = MFMA16(af[i], bfv[j], acc[i][j]);
    }

#pragma unroll
    for (int i = 0; i < 4; ++i)
#pragma unroll
        for (int j = 0; j < 4; ++j)
#pragma unroll
            for (int r = 0; r < 4; ++r) {
                int row = bm * 128 + wm + i * 16 + quad * 4 + r;
                int col = bn * 128 + wn + j * 16 + lr;
                float v = acc[i][j][r];
                if (EPI == 0) {
                    int tens = col >> 11, h = (col >> 7) & 15, e = col & 127;
                    int b = row >> 12, t = row & 4095;
                    long long dst = (((long long)(b * 16 + h)) * 4096 + t) * 128 + e;
                    unsigned short* P = (tens == 0) ? Qp : ((tens == 1) ? Kp : Vp);
                    P[dst] = f2bf(v);
                } else if (EPI == 1) {
                    v = 1.0f / (1.0f + __expf(-v));
                    ((unsigned short*)Cv)[(long long)row * N + col] = f2bf(v);
                } else {
                    ((float*)Cv)[(long long)row * N + col] = v;
                }
            }
}

// ---------------- RMSNorm + RoPE on q,k (in place, [b][h][t][d]) -----------
__global__ __launch_bounds__(256) void norm_rope(
    unsigned short* __restrict__ Qp, unsigned short* __restrict__ Kp,
    const float* __restrict__ qw, const float* __restrict__ kw,
    const int* __restrict__ pos_ids)
{
    const int bid  = blockIdx.x;            // b*16384 + h*1024 + tg
    const int tg   = bid & 1023, h = (bid >> 10) & 15, b = bid >> 14;
    const int wave = threadIdx.x >> 6, lane = threadIdx.x & 63;
    const int t    = tg * 4 + wave;
    const long long rowbase = (((long long)(b * 16 + h)) * 4096 + t) * 128;
    const int pos = pos_ids[b * 4096 + t];
    const int d0  = lane * 2;

    float c0 = 1.f, s0 = 0.f, c1 = 1.f, s1 = 0.f;
    if (lane < 32) {
        float fj0 = (float)(d0 & 31), fj1 = (float)((d0 + 1) & 31);
        float if0 = exp2f(-fj0 * 0.4152410118609203f);  // log2(10000)/32
        float if1 = exp2f(-fj1 * 0.4152410118609203f);
        sincosf((float)pos * if0, &s0, &c0);
        sincosf((float)pos * if1, &s1, &c1);
    }
    const float w0q = qw[d0], w1q = qw[d0 + 1];
    const float w0k = kw[d0], w1k = kw[d0 + 1];

#pragma unroll
    for (int which = 0; which < 2; ++which) {
        unsigned short* P = which ? Kp : Qp;
        float w0 = which ? w0k : w0q, w1 = which ? w1k : w1q;
        unsigned u = *(const unsigned*)(P + rowbase + d0);
        float x0 = bf2f(u & 0xFFFF), x1 = bf2f(u >> 16);
        float ss = x0 * x0 + x1 * x1;
#pragma unroll
        for (int off = 32; off; off >>= 1) ss += __shfl_xor(ss, off);
        float r  = rsqrtf(ss * (1.0f / 128.0f) + 1e-6f);
        float xn0 = x0 * r * w0;
        float xn1 = x1 * r * w1;
        float p0 = __shfl_xor(xn0, 16);
        float p1 = __shfl_xor(xn1, 16);
        float y0, y1;
        if (d0 < 32)      { y0 = xn0 * c0 - p0 * s0; y1 = xn1 * c1 - p1 * s1; }
        else if (d0 < 64) { y0 = xn0 * c0 + p0 * s0; y1 = xn1 * c1 + p1 * s1; }
        else              { y0 = xn0; y1 = xn1; }
        if (which == 0) { y0 *= 0.08838834764831845f; y1 *= 0.08838834764831845f; }
        *(unsigned*)(P + rowbase + d0) =
            (unsigned)f2bf(y0) | ((unsigned)f2bf(y1) << 16);
    }
}

// ---------------- GLA phase A: per-chunk intra + update matrix -------------
// grid = B*H*64 blocks, one per (b,h,chunk). Computes:
//   o_intra[c][e] = sum_{c2<=c} (q~[c]·k[c2]) exp(-g c2) * v[c2][e]  -> Oint
//   UT[e][d]      = sum_c v[c][e] * k[c][d] * exp(g(64-c))           -> Ubuf
// where q~[c] = q[c]*exp(g c). Row pads (136/72) keep LDS 2-way conflict-free.
__global__ __launch_bounds__(256) void gla_chunk(
    const unsigned short* __restrict__ Qp, const unsigned short* __restrict__ Kp,
    const unsigned short* __restrict__ Vp,
    unsigned short* __restrict__ Oint, unsigned short* __restrict__ Ubuf)
{
    __shared__ __attribute__((aligned(16))) unsigned short sK[64 * 136];
    __shared__ __attribute__((aligned(16))) unsigned short sVT[128 * 72];
    __shared__ __attribute__((aligned(16))) unsigned short sKT[128 * 72];
    __shared__ __attribute__((aligned(16))) unsigned short sAtt[64 * 72];

    const int bid = blockIdx.x;
    const int n = bid & 63, h = (bid >> 6) & 15, b = bid >> 10;
    const int tid = threadIdx.x, wave = tid >> 6, lane = tid & 63;
    const int quad = lane >> 4, lr = lane & 15;
    const float gl2 = -exp2f(-0.5f * (float)(h + 1)) * GSCALE * LOG2E;

    const long long rb = (((long long)(b * 16 + h)) * 4096 + (long long)n * 64) * 128;

    // per-lane q~ A-fragments (rows cS = wave*16+lr)
    const int cS = wave * 16 + lr;
    const float qsc = exp2f(gl2 * (float)cS);
    bf16x8 qf[4];
#pragma unroll
    for (int ks = 0; ks < 4; ++ks) {
        union { uint4 v; unsigned short s[8]; } in, ou;
        in.v = *(const uint4*)(Qp + rb + cS * 128 + ks * 32 + quad * 8);
#pragma unroll
        for (int j = 0; j < 8; ++j) ou.s[j] = f2bf(bf2f(in.s[j]) * qsc);
        qf[ks] = *(bf16x8*)&ou;
    }
    // stage sK raw (64x128, padded 136)
#pragma unroll
    for (int rr = 0; rr < 4; ++rr) {
        int idx = rr * 256 + tid;
        int c = idx >> 4, d8 = (idx & 15) << 3;
        *(uint4*)(sK + c * 136 + d8) = *(const uint4*)(Kp + rb + c * 128 + d8);
    }
    // stage sVT (v^T) and sKT (k^T with exp(g(64-c)) folded)
#pragma unroll
    for (int rr = 0; rr < 4; ++rr) {
        int idx = rr * 256 + tid;
        int c = idx & 63, g8 = (idx >> 6) << 3;
        union { uint4 v; unsigned short s[8]; } vv, kk;
        vv.v = *(const uint4*)(Vp + rb + c * 128 + g8);
        kk.v = *(const uint4*)(Kp + rb + c * 128 + g8);
        float kdsc = exp2f(gl2 * (float)(64 - c));
#pragma unroll
        for (int j = 0; j < 8; ++j) {
            sVT[(g8 + j) * 72 + c] = vv.s[j];
            sKT[(g8 + j) * 72 + c] = f2bf(bf2f(kk.s[j]) * kdsc);
        }
    }
    __syncthreads();

    // att~ = q~ @ k^T
    f32x4 aacc[4] = {};
#pragma unroll
    for (int nj = 0; nj < 4; ++nj)
#pragma unroll
        for (int ks = 0; ks < 4; ++ks) {
            bf16x8 bf = *(const bf16x8*)(sK + (nj * 16 + lr) * 136 + ks * 32 + quad * 8);
            aacc[nj] = MFMA16(qf[ks], bf, aacc[nj]);
        }
    // masked att -> sAtt (bf16)
#pragma unroll
    for (int nj = 0; nj < 4; ++nj) {
        int c2 = nj * 16 + lr;
        float colf = exp2f(-gl2 * (float)c2);
#pragma unroll
        for (int r = 0; r < 4; ++r) {
            int c = wave * 16 + quad * 4 + r;
            sAtt[c * 72 + c2] = f2bf((c >= c2) ? aacc[nj][r] * colf : 0.0f);
        }
    }
    // UT[e][d] via MFMA (A = v^T rows e, B = k'^T rows d)
    f32x4 Sacc[2][8] = {};
#pragma unroll
    for (int me = 0; me < 2; ++me)
#pragma unroll
        for (int ks = 0; ks < 2; ++ks) {
            bf16x8 af = *(const bf16x8*)(sVT + (wave * 32 + me * 16 + lr) * 72 + ks * 32 + quad * 8);
#pragma unroll
            for (int dj = 0; dj < 8; ++dj) {
                bf16x8 bf = *(const bf16x8*)(sKT + (dj * 16 + lr) * 72 + ks * 32 + quad * 8);
                Sacc[me][dj] = MFMA16(af, bf, Sacc[me][dj]);
            }
        }
    // write U (bf16, [bh][n][e][d])
    const long long ub = ((long long)((b * 16 + h) * 64 + n)) * 16384;
#pragma unroll
    for (int me = 0; me < 2; ++me)
#pragma unroll
        for (int r = 0; r < 4; ++r) {
            int e = wave * 32 + me * 16 + quad * 4 + r;
#pragma unroll
            for (int dj = 0; dj < 8; ++dj)
                Ubuf[ub + e * 128 + dj * 16 + lr] = f2bf(Sacc[me][dj][r]);
        }
    __syncthreads();

    // intra: o = att @ v  (A = sAtt rows c, B = sVT rows e)
    f32x4 oacc[8] = {};
#pragma unroll
    for (int ks = 0; ks < 2; ++ks) {
        bf16x8 af = *(const bf16x8*)(sAtt + cS * 72 + ks * 32 + quad * 8);
#pragma unroll
        for (int ej = 0; ej < 8; ++ej) {
            bf16x8 bf = *(const bf16x8*)(sVT + (ej * 16 + lr) * 72 + ks * 32 + quad * 8);
            oacc[ej] = MFMA16(af, bf, oacc[ej]);
        }
    }
    // write o_intra [b][t][h*128+e]
#pragma unroll
    for (int ej = 0; ej < 8; ++ej)
#pragma unroll
        for (int r = 0; r < 4; ++r) {
            int c = wave * 16 + quad * 4 + r;
            long long off = ((long long)(b * 4096 + n * 64 + c)) * 2048 + h * 128 + ej * 16 + lr;
            Oint[off] = f2bf(oacc[ej][r]);
        }
}

// ---------------- GLA phase B: chunk-level prefix scan ---------------------
// grid = B*H*8 blocks; block owns a 16-e-row slice of the 128x128 state.
// ST[n] = state ENTERING chunk n: s_0=0, s_{n+1} = chd*s_n + U_n. f32 regs.
__global__ __launch_bounds__(256) void gla_scan(
    const unsigned short* __restrict__ Ubuf, unsigned short* __restrict__ STbuf)
{
    const int bid = blockIdx.x;
    const int es = bid & 7, bh = bid >> 3;
    const int h = bh & 15;
    const float gl2 = -exp2f(-0.5f * (float)(h + 1)) * GSCALE * LOG2E;
    const float chd = exp2f(gl2 * 64.0f);
    const int tid = threadIdx.x;
    const long long base = (long long)bh * 64 * 16384 + es * 2048 + tid * 8;
    float st[8] = {};
    for (int n = 0; n < 64; ++n) {
        long long a = base + (long long)n * 16384;
        union { uint4 v; unsigned short s[8]; } u, o;
        u.v = *(const uint4*)(Ubuf + a);
#pragma unroll
        for (int j = 0; j < 8; ++j) o.s[j] = f2bf(st[j]);
        *(uint4*)(STbuf + a) = o.v;
#pragma unroll
        for (int j = 0; j < 8; ++j) st[j] = st[j] * chd + bf2f(u.s[j]);
    }
}

// ---------------- GLA phase C: inter + group-RMSNorm * gate ----------------
// grid = B*H*64; o = o_intra + q~ @ ST^T, then per-head rmsnorm * gate -> Ob
__global__ __launch_bounds__(256) void gla_inter(
    const unsigned short* __restrict__ Qp, const unsigned short* __restrict__ STbuf,
    unsigned short* __restrict__ Ob, const unsigned short* __restrict__ Gb,
    const float* __restrict__ W)
{
    __shared__ __attribute__((aligned(16))) unsigned short sST[128 * 136];
    const int bid = blockIdx.x;
    const int n = bid & 63, h = (bid >> 6) & 15, b = bid >> 10;
    const int tid = threadIdx.x, wave = tid >> 6, lane = tid & 63;
    const int quad = lane >> 4, lr = lane & 15;
    const float gl2 = -exp2f(-0.5f * (float)(h + 1)) * GSCALE * LOG2E;
    const long long rb = (((long long)(b * 16 + h)) * 4096 + (long long)n * 64) * 128;
    const long long stb = ((long long)((b * 16 + h) * 64 + n)) * 16384;

    // stage ST [e][d] padded
#pragma unroll
    for (int rr = 0; rr < 8; ++rr) {
        int idx = rr * 256 + tid;
        int row = idx >> 4, d8 = (idx & 15) << 3;
        *(uint4*)(sST + row * 136 + d8) = *(const uint4*)(STbuf + stb + row * 128 + d8);
    }
    // q~ A-fragments
    const int cS = wave * 16 + lr;
    const float qsc = exp2f(gl2 * (float)cS);
    bf16x8 qf[4];
#pragma unroll
    for (int ks = 0; ks < 4; ++ks) {
        union { uint4 v; unsigned short s[8]; } in, ou;
        in.v = *(const uint4*)(Qp + rb + cS * 128 + ks * 32 + quad * 8);
#pragma unroll
        for (int j = 0; j < 8; ++j) ou.s[j] = f2bf(bf2f(in.s[j]) * qsc);
        qf[ks] = *(bf16x8*)&ou;
    }
    __syncthreads();

    f32x4 oacc[8] = {};
#pragma unroll
    for (int ks = 0; ks < 4; ++ks)
#pragma unroll
        for (int ej = 0; ej < 8; ++ej) {
            bf16x8 bf = *(const bf16x8*)(sST + (ej * 16 + lr) * 136 + ks * 32 + quad * 8);
            oacc[ej] = MFMA16(qf[ks], bf, oacc[ej]);
        }

    float w[8];
#pragma unroll
    for (int ej = 0; ej < 8; ++ej) w[ej] = W[h * 128 + ej * 16 + lr];

    float ss[4] = {};
#pragma unroll
    for (int r = 0; r < 4; ++r) {
        int c = wave * 16 + quad * 4 + r;
        long long off = ((long long)(b * 4096 + n * 64 + c)) * 2048 + h * 128;
#pragma unroll
        for (int ej = 0; ej < 8; ++ej) {
            float v = oacc[ej][r] + bf2f(Ob[off + ej * 16 + lr]);
            oacc[ej][r] = v;
            ss[r] += v * v;
        }
    }
#pragma unroll
    for (int r = 0; r < 4; ++r) {
#pragma unroll
        for (int o2 = 1; o2 < 16; o2 <<= 1) ss[r] += __shfl_xor(ss[r], o2);
        float rn = rsqrtf(ss[r] * (1.0f / 128.0f) + 1e-6f);
        int c = wave * 16 + quad * 4 + r;
        long long off = ((long long)(b * 4096 + n * 64 + c)) * 2048 + h * 128;
#pragma unroll
        for (int ej = 0; ej < 8; ++ej) {
            float g = bf2f(Gb[off + ej * 16 + lr]);
            Ob[off + ej * 16 + lr] = f2bf(oacc[ej][r] * rn * w[ej] * g);
        }
    }
}

// ---------------- launcher ----------------
extern "C" void kernel_launch(void* const* d_in, const int* in_sizes, int n_in,
                              void* d_out, int out_size, void* d_ws, size_t ws_size,
                              hipStream_t stream)
{
    const float* hid   = (const float*)d_in[0];
    const float* w_qkv = (const float*)d_in[1];
    const float* q_ln  = (const float*)d_in[2];
    const float* k_ln  = (const float*)d_in[3];
    const float* g_nw  = (const float*)d_in[4];
    const float* w_g   = (const float*)d_in[5];
    const float* w_d   = (const float*)d_in[6];
    const int*   pos   = (const int*)d_in[7];

    const size_t PLANE = (size_t)2 * 16 * 4096 * 128;  // 16.78M elems
    unsigned short* Qp    = (unsigned short*)d_ws;
    unsigned short* Kp    = Qp + PLANE;
    unsigned short* Vp    = Kp + PLANE;
    unsigned short* Ob    = Vp + PLANE;
    unsigned short* Gb    = Ob + PLANE;
    unsigned short* hidb  = Gb + PLANE;                  // 8192*2048
    unsigned short* wqkvb = hidb + (size_t)8192 * 2048;  // 6144*2048
    unsigned short* wgb   = wqkvb + (size_t)6144 * 2048; // 2048*2048
    unsigned short* wdb   = wgb + (size_t)2048 * 2048;   // 2048*2048
    // aliases (lifetimes disjoint by stream order):
    unsigned short* Ubuf  = hidb;  // 33.55M elems == hidb+wqkvb+wgb exactly
    unsigned short* STbuf = Kp;    // 33.55M elems == Kp+Vp

    dim3 blk(256);
    // f32 -> bf16 conversions
    cvt_f32_bf16<<<(8192 * 2048 / 4 + 255) / 256, blk, 0, stream>>>(hid, hidb, 8192 * 2048 / 4);
    cvt_f32_bf16<<<(6144 * 2048 / 4 + 255) / 256, blk, 0, stream>>>(w_qkv, wqkvb, 6144 * 2048 / 4);
    cvt_f32_bf16<<<(2048 * 2048 / 4 + 255) / 256, blk, 0, stream>>>(w_g, wgb, 2048 * 2048 / 4);
    cvt_f32_bf16<<<(2048 * 2048 / 4 + 255) / 256, blk, 0, stream>>>(w_d, wdb, 2048 * 2048 / 4);

    // QKV projection, scatter to [b][h][t][d]
    gemm_bt<0><<<dim3(48, 64), blk, 0, stream>>>(hidb, wqkvb, nullptr, Qp, Kp, Vp,
                                                 8192, 6144, 2048);
    // q/k rmsnorm + rope (+ q * D^-0.5), in place
    norm_rope<<<32768, blk, 0, stream>>>(Qp, Kp, q_ln, k_ln, pos);
    // gate projection + sigmoid (must finish before Ubuf overwrites hidb)
    gemm_bt<1><<<dim3(16, 64), blk, 0, stream>>>(hidb, wgb, Gb, nullptr, nullptr,
                                                 nullptr, 8192, 2048, 2048);
    // GLA: per-chunk work (parallel) -> scan (cheap) -> inter + norm*gate
    gla_chunk<<<2048, blk, 0, stream>>>(Qp, Kp, Vp, Ob, Ubuf);
    gla_scan<<<256, blk, 0, stream>>>(Ubuf, STbuf);
    gla_inter<<<2048, blk, 0, stream>>>(Qp, STbuf, Ob, Gb, g_nw);
    // output projection -> f32 d_out
    gemm_bt<2><<<dim3(16, 64), blk, 0, stream>>>(Ob, wdb, d_out, nullptr, nullptr,
                                                 nullptr, 8192, 2048, 2048);
}

// Round 4
// 681.336 us; speedup vs baseline: 1.4263x; 1.1640x over previous
//
#include <hip/hip_runtime.h>
#include <math.h>

// ---------------- common helpers ----------------
typedef short bf16x8 __attribute__((ext_vector_type(8)));
typedef float f32x4 __attribute__((ext_vector_type(4)));

#define LOG2E 1.4426950408889634f
#define GSCALE 0.6451712903225806f   /* 1 - 11/31 + 1e-5 */

__device__ __forceinline__ float bf2f(unsigned short h) {
    union { unsigned u; float f; } v; v.u = ((unsigned)h) << 16; return v.f;
}
__device__ __forceinline__ unsigned short f2bf(float f) {
    union { float f; unsigned u; } v; v.f = f;
    unsigned r = v.u + 0x7FFFu + ((v.u >> 16) & 1u);
    return (unsigned short)(r >> 16);
}

#define GLD16(lds, g)                                                          \
    __builtin_amdgcn_global_load_lds(                                          \
        (const __attribute__((address_space(1))) void*)(g),                    \
        (__attribute__((address_space(3))) void*)(lds), 16, 0, 0)

#define MFMA16(a, b, c) __builtin_amdgcn_mfma_f32_16x16x32_bf16(a, b, c, 0, 0, 0)

// ---------------- fused f32 -> bf16 conversion (4 srcs, contiguous dst) ----
struct us4 { unsigned short a, b, c, d; };
__global__ __launch_bounds__(256) void cvt4_f32_bf16(
    const float* __restrict__ s0, const float* __restrict__ s1,
    const float* __restrict__ s2, const float* __restrict__ s3,
    unsigned short* __restrict__ dst, int c0, int c1, int c2, int n4)
{
    int i = blockIdx.x * 256 + threadIdx.x;
    if (i >= n4) return;
    const float* s; int off;
    if (i < c0)      { s = s0; off = i; }
    else if (i < c1) { s = s1; off = i - c0; }
    else if (i < c2) { s = s2; off = i - c1; }
    else             { s = s3; off = i - c2; }
    float4 v = ((const float4*)s)[off];
    us4 o = { f2bf(v.x), f2bf(v.y), f2bf(v.z), f2bf(v.w) };
    ((us4*)dst)[i] = o;
}

// ---------------- GEMM: C[M][N] = A[M][K] @ Bt[N][K]^T (bf16, f32 acc) ------
// BK=64, XOR-swizzled LDS (row stride 64 elems = 128 B = full bank wrap;
// slot g holds global group g^(row&7) -> conflict-free ds_read_b128).
// EPI 0: col<6144 -> scatter Q/K/V [b][h][t][d]; col>=6144 -> sigmoid -> Gb
// EPI 2: plain f32 -> C
template <int EPI>
__global__ __launch_bounds__(256) void gemm_bt(
    const unsigned short* __restrict__ A, const unsigned short* __restrict__ Bt,
    void* __restrict__ Cv,
    unsigned short* __restrict__ Qp, unsigned short* __restrict__ Kp,
    unsigned short* __restrict__ Vp, unsigned short* __restrict__ Gb,
    int M, int N, int K)
{
    __shared__ __attribute__((aligned(16))) unsigned short lA[128 * 64];
    __shared__ __attribute__((aligned(16))) unsigned short lB[128 * 64];
    const int tid  = threadIdx.x;
    const int bn   = blockIdx.x, bm = blockIdx.y;
    const int lane = tid & 63, wave = tid >> 6;
    const int quad = lane >> 4, lr = lane & 15;
    const int wm   = (wave >> 1) * 64, wn = (wave & 1) * 64;
    const int lsw  = lr & 7;          // fragment-read swizzle key
    f32x4 acc[4][4] = {};

    const unsigned short* Abase = A + ((long long)bm * 128) * K;
    const unsigned short* Bbase = Bt + ((long long)bn * 128) * K;

    for (int kt = 0; kt < K; kt += 64) {
        __syncthreads();
#pragma unroll
        for (int r = 0; r < 4; ++r) {
            int c   = r * 256 + tid;
            int row = c >> 3, g = c & 7;
            int gg  = (g ^ (row & 7)) * 8;
            GLD16(lA + c * 8, Abase + (long long)row * K + kt + gg);
            GLD16(lB + c * 8, Bbase + (long long)row * K + kt + gg);
        }
        __syncthreads();
#pragma unroll
        for (int s = 0; s < 2; ++s) {
            bf16x8 af[4], bfv[4];
#pragma unroll
            for (int i = 0; i < 4; ++i)
                af[i] = *(const bf16x8*)(lA + (wm + i * 16 + lr) * 64 +
                                         (((s * 4 + quad) ^ lsw) * 8));
#pragma unroll
            for (int j = 0; j < 4; ++j)
                bfv[j] = *(const bf16x8*)(lB + (wn + j * 16 + lr) * 64 +
                                          (((s * 4 + quad) ^ lsw) * 8));
#pragma unroll
            for (int i = 0; i < 4; ++i)
#pragma unroll
                for (int j = 0; j < 4; ++j)
                    acc[i][j] = MFMA16(af[i], bfv[j], acc[i][j]);
        }
    }

#pragma unroll
    for (int i = 0; i < 4; ++i)
#pragma unroll
        for (int j = 0; j < 4; ++j)
#pragma unroll
            for (int r = 0; r < 4; ++r) {
                int row = bm * 128 + wm + i * 16 + quad * 4 + r;
                int col = bn * 128 + wn + j * 16 + lr;
                float v = acc[i][j][r];
                if (EPI == 0) {
                    if (col < 6144) {
                        int tens = col >> 11, h = (col >> 7) & 15, e = col & 127;
                        int b = row >> 12, t = row & 4095;
                        long long dst = (((long long)(b * 16 + h)) * 4096 + t) * 128 + e;
                        unsigned short* P = (tens == 0) ? Qp : ((tens == 1) ? Kp : Vp);
                        P[dst] = f2bf(v);
                    } else {
                        v = 1.0f / (1.0f + __expf(-v));
                        Gb[(long long)row * 2048 + (col - 6144)] = f2bf(v);
                    }
                } else {
                    ((float*)Cv)[(long long)row * N + col] = v;
                }
            }
}

// ---------------- RMSNorm + RoPE on q,k (in place, [b][h][t][d]) -----------
__global__ __launch_bounds__(256) void norm_rope(
    unsigned short* __restrict__ Qp, unsigned short* __restrict__ Kp,
    const float* __restrict__ qw, const float* __restrict__ kw,
    const int* __restrict__ pos_ids)
{
    const int bid  = blockIdx.x;            // b*16384 + h*1024 + tg
    const int tg   = bid & 1023, h = (bid >> 10) & 15, b = bid >> 14;
    const int wave = threadIdx.x >> 6, lane = threadIdx.x & 63;
    const int t    = tg * 4 + wave;
    const long long rowbase = (((long long)(b * 16 + h)) * 4096 + t) * 128;
    const int pos = pos_ids[b * 4096 + t];
    const int d0  = lane * 2;

    float c0 = 1.f, s0 = 0.f, c1 = 1.f, s1 = 0.f;
    if (lane < 32) {
        float fj0 = (float)(d0 & 31), fj1 = (float)((d0 + 1) & 31);
        float if0 = exp2f(-fj0 * 0.4152410118609203f);  // log2(10000)/32
        float if1 = exp2f(-fj1 * 0.4152410118609203f);
        sincosf((float)pos * if0, &s0, &c0);
        sincosf((float)pos * if1, &s1, &c1);
    }
    const float w0q = qw[d0], w1q = qw[d0 + 1];
    const float w0k = kw[d0], w1k = kw[d0 + 1];

#pragma unroll
    for (int which = 0; which < 2; ++which) {
        unsigned short* P = which ? Kp : Qp;
        float w0 = which ? w0k : w0q, w1 = which ? w1k : w1q;
        unsigned u = *(const unsigned*)(P + rowbase + d0);
        float x0 = bf2f(u & 0xFFFF), x1 = bf2f(u >> 16);
        float ss = x0 * x0 + x1 * x1;
#pragma unroll
        for (int off = 32; off; off >>= 1) ss += __shfl_xor(ss, off);
        float r  = rsqrtf(ss * (1.0f / 128.0f) + 1e-6f);
        float xn0 = x0 * r * w0;
        float xn1 = x1 * r * w1;
        float p0 = __shfl_xor(xn0, 16);
        float p1 = __shfl_xor(xn1, 16);
        float y0, y1;
        if (d0 < 32)      { y0 = xn0 * c0 - p0 * s0; y1 = xn1 * c1 - p1 * s1; }
        else if (d0 < 64) { y0 = xn0 * c0 + p0 * s0; y1 = xn1 * c1 + p1 * s1; }
        else              { y0 = xn0; y1 = xn1; }
        if (which == 0) { y0 *= 0.08838834764831845f; y1 *= 0.08838834764831845f; }
        *(unsigned*)(P + rowbase + d0) =
            (unsigned)f2bf(y0) | ((unsigned)f2bf(y1) << 16);
    }
}

// ---------------- GLA phase A: per-chunk intra + update matrix -------------
__global__ __launch_bounds__(256) void gla_chunk(
    const unsigned short* __restrict__ Qp, const unsigned short* __restrict__ Kp,
    const unsigned short* __restrict__ Vp,
    unsigned short* __restrict__ Oint, unsigned short* __restrict__ Ubuf)
{
    __shared__ __attribute__((aligned(16))) unsigned short sK[64 * 136];
    __shared__ __attribute__((aligned(16))) unsigned short sVT[128 * 72];
    __shared__ __attribute__((aligned(16))) unsigned short sKT[128 * 72];
    __shared__ __attribute__((aligned(16))) unsigned short sAtt[64 * 72];

    const int bid = blockIdx.x;
    const int n = bid & 63, h = (bid >> 6) & 15, b = bid >> 10;
    const int tid = threadIdx.x, wave = tid >> 6, lane = tid & 63;
    const int quad = lane >> 4, lr = lane & 15;
    const float gl2 = -exp2f(-0.5f * (float)(h + 1)) * GSCALE * LOG2E;

    const long long rb = (((long long)(b * 16 + h)) * 4096 + (long long)n * 64) * 128;

    const int cS = wave * 16 + lr;
    const float qsc = exp2f(gl2 * (float)cS);
    bf16x8 qf[4];
#pragma unroll
    for (int ks = 0; ks < 4; ++ks) {
        union { uint4 v; unsigned short s[8]; } in, ou;
        in.v = *(const uint4*)(Qp + rb + cS * 128 + ks * 32 + quad * 8);
#pragma unroll
        for (int j = 0; j < 8; ++j) ou.s[j] = f2bf(bf2f(in.s[j]) * qsc);
        qf[ks] = *(bf16x8*)&ou;
    }
#pragma unroll
    for (int rr = 0; rr < 4; ++rr) {
        int idx = rr * 256 + tid;
        int c = idx >> 4, d8 = (idx & 15) << 3;
        *(uint4*)(sK + c * 136 + d8) = *(const uint4*)(Kp + rb + c * 128 + d8);
    }
#pragma unroll
    for (int rr = 0; rr < 4; ++rr) {
        int idx = rr * 256 + tid;
        int c = idx & 63, g8 = (idx >> 6) << 3;
        union { uint4 v; unsigned short s[8]; } vv, kk;
        vv.v = *(const uint4*)(Vp + rb + c * 128 + g8);
        kk.v = *(const uint4*)(Kp + rb + c * 128 + g8);
        float kdsc = exp2f(gl2 * (float)(64 - c));
#pragma unroll
        for (int j = 0; j < 8; ++j) {
            sVT[(g8 + j) * 72 + c] = vv.s[j];
            sKT[(g8 + j) * 72 + c] = f2bf(bf2f(kk.s[j]) * kdsc);
        }
    }
    __syncthreads();

    f32x4 aacc[4] = {};
#pragma unroll
    for (int nj = 0; nj < 4; ++nj)
#pragma unroll
        for (int ks = 0; ks < 4; ++ks) {
            bf16x8 bf = *(const bf16x8*)(sK + (nj * 16 + lr) * 136 + ks * 32 + quad * 8);
            aacc[nj] = MFMA16(qf[ks], bf, aacc[nj]);
        }
#pragma unroll
    for (int nj = 0; nj < 4; ++nj) {
        int c2 = nj * 16 + lr;
        float colf = exp2f(-gl2 * (float)c2);
#pragma unroll
        for (int r = 0; r < 4; ++r) {
            int c = wave * 16 + quad * 4 + r;
            sAtt[c * 72 + c2] = f2bf((c >= c2) ? aacc[nj][r] * colf : 0.0f);
        }
    }
    f32x4 Sacc[2][8] = {};
#pragma unroll
    for (int me = 0; me < 2; ++me)
#pragma unroll
        for (int ks = 0; ks < 2; ++ks) {
            bf16x8 af = *(const bf16x8*)(sVT + (wave * 32 + me * 16 + lr) * 72 + ks * 32 + quad * 8);
#pragma unroll
            for (int dj = 0; dj < 8; ++dj) {
                bf16x8 bf = *(const bf16x8*)(sKT + (dj * 16 + lr) * 72 + ks * 32 + quad * 8);
                Sacc[me][dj] = MFMA16(af, bf, Sacc[me][dj]);
            }
        }
    const long long ub = ((long long)((b * 16 + h) * 64 + n)) * 16384;
#pragma unroll
    for (int me = 0; me < 2; ++me)
#pragma unroll
        for (int r = 0; r < 4; ++r) {
            int e = wave * 32 + me * 16 + quad * 4 + r;
#pragma unroll
            for (int dj = 0; dj < 8; ++dj)
                Ubuf[ub + e * 128 + dj * 16 + lr] = f2bf(Sacc[me][dj][r]);
        }
    __syncthreads();

    f32x4 oacc[8] = {};
#pragma unroll
    for (int ks = 0; ks < 2; ++ks) {
        bf16x8 af = *(const bf16x8*)(sAtt + cS * 72 + ks * 32 + quad * 8);
#pragma unroll
        for (int ej = 0; ej < 8; ++ej) {
            bf16x8 bf = *(const bf16x8*)(sVT + (ej * 16 + lr) * 72 + ks * 32 + quad * 8);
            oacc[ej] = MFMA16(af, bf, oacc[ej]);
        }
    }
#pragma unroll
    for (int ej = 0; ej < 8; ++ej)
#pragma unroll
        for (int r = 0; r < 4; ++r) {
            int c = wave * 16 + quad * 4 + r;
            long long off = ((long long)(b * 4096 + n * 64 + c)) * 2048 + h * 128 + ej * 16 + lr;
            Oint[off] = f2bf(oacc[ej][r]);
        }
}

// ---------------- GLA phase B: chunk-level prefix scan ---------------------
__global__ __launch_bounds__(256) void gla_scan(
    const unsigned short* __restrict__ Ubuf, unsigned short* __restrict__ STbuf)
{
    const int bid = blockIdx.x;
    const int es = bid & 7, bh = bid >> 3;
    const int h = bh & 15;
    const float gl2 = -exp2f(-0.5f * (float)(h + 1)) * GSCALE * LOG2E;
    const float chd = exp2f(gl2 * 64.0f);
    const int tid = threadIdx.x;
    const long long base = (long long)bh * 64 * 16384 + es * 2048 + tid * 8;
    float st[8] = {};
    for (int n = 0; n < 64; ++n) {
        long long a = base + (long long)n * 16384;
        union { uint4 v; unsigned short s[8]; } u, o;
        u.v = *(const uint4*)(Ubuf + a);
#pragma unroll
        for (int j = 0; j < 8; ++j) o.s[j] = f2bf(st[j]);
        *(uint4*)(STbuf + a) = o.v;
#pragma unroll
        for (int j = 0; j < 8; ++j) st[j] = st[j] * chd + bf2f(u.s[j]);
    }
}

// ---------------- GLA phase C: inter + group-RMSNorm * gate ----------------
__global__ __launch_bounds__(256) void gla_inter(
    const unsigned short* __restrict__ Qp, const unsigned short* __restrict__ STbuf,
    unsigned short* __restrict__ Ob, const unsigned short* __restrict__ Gb,
    const float* __restrict__ W)
{
    __shared__ __attribute__((aligned(16))) unsigned short sST[128 * 136];
    const int bid = blockIdx.x;
    const int n = bid & 63, h = (bid >> 6) & 15, b = bid >> 10;
    const int tid = threadIdx.x, wave = tid >> 6, lane = tid & 63;
    const int quad = lane >> 4, lr = lane & 15;
    const float gl2 = -exp2f(-0.5f * (float)(h + 1)) * GSCALE * LOG2E;
    const long long rb = (((long long)(b * 16 + h)) * 4096 + (long long)n * 64) * 128;
    const long long stb = ((long long)((b * 16 + h) * 64 + n)) * 16384;

#pragma unroll
    for (int rr = 0; rr < 8; ++rr) {
        int idx = rr * 256 + tid;
        int row = idx >> 4, d8 = (idx & 15) << 3;
        *(uint4*)(sST + row * 136 + d8) = *(const uint4*)(STbuf + stb + row * 128 + d8);
    }
    const int cS = wave * 16 + lr;
    const float qsc = exp2f(gl2 * (float)cS);
    bf16x8 qf[4];
#pragma unroll
    for (int ks = 0; ks < 4; ++ks) {
        union { uint4 v; unsigned short s[8]; } in, ou;
        in.v = *(const uint4*)(Qp + rb + cS * 128 + ks * 32 + quad * 8);
#pragma unroll
        for (int j = 0; j < 8; ++j) ou.s[j] = f2bf(bf2f(in.s[j]) * qsc);
        qf[ks] = *(bf16x8*)&ou;
    }
    __syncthreads();

    f32x4 oacc[8] = {};
#pragma unroll
    for (int ks = 0; ks < 4; ++ks)
#pragma unroll
        for (int ej = 0; ej < 8; ++ej) {
            bf16x8 bf = *(const bf16x8*)(sST + (ej * 16 + lr) * 136 + ks * 32 + quad * 8);
            oacc[ej] = MFMA16(qf[ks], bf, oacc[ej]);
        }

    float w[8];
#pragma unroll
    for (int ej = 0; ej < 8; ++ej) w[ej] = W[h * 128 + ej * 16 + lr];

    float ss[4] = {};
#pragma unroll
    for (int r = 0; r < 4; ++r) {
        int c = wave * 16 + quad * 4 + r;
        long long off = ((long long)(b * 4096 + n * 64 + c)) * 2048 + h * 128;
#pragma unroll
        for (int ej = 0; ej < 8; ++ej) {
            float v = oacc[ej][r] + bf2f(Ob[off + ej * 16 + lr]);
            oacc[ej][r] = v;
            ss[r] += v * v;
        }
    }
#pragma unroll
    for (int r = 0; r < 4; ++r) {
#pragma unroll
        for (int o2 = 1; o2 < 16; o2 <<= 1) ss[r] += __shfl_xor(ss[r], o2);
        float rn = rsqrtf(ss[r] * (1.0f / 128.0f) + 1e-6f);
        int c = wave * 16 + quad * 4 + r;
        long long off = ((long long)(b * 4096 + n * 64 + c)) * 2048 + h * 128;
#pragma unroll
        for (int ej = 0; ej < 8; ++ej) {
            float g = bf2f(Gb[off + ej * 16 + lr]);
            Ob[off + ej * 16 + lr] = f2bf(oacc[ej][r] * rn * w[ej] * g);
        }
    }
}

// ---------------- launcher ----------------
extern "C" void kernel_launch(void* const* d_in, const int* in_sizes, int n_in,
                              void* d_out, int out_size, void* d_ws, size_t ws_size,
                              hipStream_t stream)
{
    const float* hid   = (const float*)d_in[0];
    const float* w_qkv = (const float*)d_in[1];
    const float* q_ln  = (const float*)d_in[2];
    const float* k_ln  = (const float*)d_in[3];
    const float* g_nw  = (const float*)d_in[4];
    const float* w_g   = (const float*)d_in[5];
    const float* w_d   = (const float*)d_in[6];
    const int*   pos   = (const int*)d_in[7];

    const size_t PLANE = (size_t)2 * 16 * 4096 * 128;  // 16.78M elems
    unsigned short* Qp    = (unsigned short*)d_ws;
    unsigned short* Kp    = Qp + PLANE;
    unsigned short* Vp    = Kp + PLANE;
    unsigned short* Ob    = Vp + PLANE;
    unsigned short* Gb    = Ob + PLANE;
    unsigned short* hidb  = Gb + PLANE;                  // 8192*2048
    unsigned short* wqkvb = hidb + (size_t)8192 * 2048;  // 6144*2048  (qkv ‖ gate)
    unsigned short* wgb   = wqkvb + (size_t)6144 * 2048; // 2048*2048  (contiguous!)
    unsigned short* wdb   = wgb + (size_t)2048 * 2048;   // 2048*2048
    // aliases (lifetimes disjoint by stream order):
    unsigned short* Ubuf  = hidb;  // 33.55M elems == hidb+wqkvb+wgb exactly
    unsigned short* STbuf = Kp;    // 33.55M elems == Kp+Vp

    dim3 blk(256);
    const int c0 = 8192 * 2048 / 4;                 // hid
    const int c1 = c0 + 6144 * 2048 / 4;            // w_qkv
    const int c2 = c1 + 2048 * 2048 / 4;            // w_g
    const int n4 = c2 + 2048 * 2048 / 4;            // w_d
    cvt4_f32_bf16<<<(n4 + 255) / 256, blk, 0, stream>>>(
        hid, w_qkv, w_g, w_d, hidb, c0, c1, c2, n4);

    // merged QKV+gate projection: B = [w_qkv ; w_g], N=8192
    gemm_bt<0><<<dim3(64, 64), blk, 0, stream>>>(hidb, wqkvb, nullptr, Qp, Kp, Vp,
                                                 Gb, 8192, 8192, 2048);
    // q/k rmsnorm + rope (+ q * D^-0.5), in place
    norm_rope<<<32768, blk, 0, stream>>>(Qp, Kp, q_ln, k_ln, pos);
    // GLA: per-chunk work (parallel) -> scan (cheap) -> inter + norm*gate
    gla_chunk<<<2048, blk, 0, stream>>>(Qp, Kp, Vp, Ob, Ubuf);
    gla_scan<<<256, blk, 0, stream>>>(Ubuf, STbuf);
    gla_inter<<<2048, blk, 0, stream>>>(Qp, STbuf, Ob, Gb, g_nw);
    // output projection -> f32 d_out
    gemm_bt<2><<<dim3(16, 64), blk, 0, stream>>>(Ob, wdb, d_out, nullptr, nullptr,
                                                 nullptr, nullptr, 8192, 2048, 2048);
}